// Round 4
// baseline (197.581 us; speedup 1.0000x reference)
//
#include <hip/hip_runtime.h>
#include <cstdint>
#include <cstddef>

#define BB 16384

// ---------------- Single fully-fused kernel, low-LDS edition (resubmit of
// round-3 source; round-3 bench died to a container-acquisition failure).
// Round-2 counters: OccupancyPercent 36.2% == exactly 3 blocks/CU (12/32
// waves) with LDS_Block_Size 18432 -> consistent with a 64KB effective LDS
// occupancy budget. This version cuts LDS to 10240B (-> 6 blocks/CU):
//  - two-pass member-row staging in a per-wave scratch (4 rows at a time),
//  - scratch reused as the comb buffer (disjoint wave-local lifetimes),
//  - wcomp deleted: weight recomputed from entry index (hw/sw/0),
//  - __syncthreads moved before any VMEM issue (barrier drain can't stall
//    in-flight gathers), gather iter-0 peeled so 6 loads fly under inline-Q.
__global__ __launch_bounds__(256, 6) void k_fused(
    const int* __restrict__ nodes, const int* __restrict__ hist_u,
    const int* __restrict__ hist_r, const int* __restrict__ hist_m,
    const int* __restrict__ soc_a, const int* __restrict__ soc_m,
    const float* __restrict__ features, const float* __restrict__ r_embed,
    const float* __restrict__ wg1, const float* __restrict__ bg1,
    const float* __restrict__ wg2, const float* __restrict__ bg2,
    const float* __restrict__ w1, const float* __restrict__ b1,
    float* __restrict__ out)
{
    __shared__ float wg1t[16 * 68];      // 4352B: wg1 transposed [k][d], padded
    __shared__ int   lcomp[4][96];       // 1536B: merged byte-offset list per wave
    __shared__ float scratch[4][272];    // 4352B: per-wave union:
                                         //   phase Q   : mrow[4 rows][68]
                                         //   phase out : combs[128]
    // total LDS = 10240B -> 6 blocks under a 64KB budget

    const int tid  = threadIdx.x;
    const int lane = tid & 63;
    const int wv   = tid >> 6;
    const int e    = blockIdx.x * 4 + wv;
    const int sub  = lane & 15;
    const int grp  = lane >> 4;
    const char* fB = (const char*)features;

    // ---- stage wg1 transposed (block-shared), then the ONLY barrier ----
    {
        const float4 w = ((const float4*)wg1)[tid];   // wg1[64][16]: d=tid>>2, k0=(tid&3)*4
        const int d = tid >> 2, k0 = (tid & 3) * 4;
        wg1t[(k0 + 0) * 68 + d] = w.x;
        wg1t[(k0 + 1) * 68 + d] = w.y;
        wg1t[(k0 + 2) * 68 + d] = w.z;
        wg1t[(k0 + 3) * 68 + d] = w.w;
    }
    __syncthreads();   // before any gather issue: barrier drain costs nothing

    // ---- zero-init merged list (tail entries: offset 0 = row 0) ----
    lcomp[wv][lane] = 0;
    if (lane < 32) lcomp[wv][64 + lane] = 0;

    // ---- index loads (issue ASAP) ----
    int nd = (lane < 8) ? nodes[e * 8 + lane] : 0;
    int hu = 0, hr = 0, hmv = 0;
    if (lane < 50) {
        hu  = hist_u[e * 50 + lane];
        hr  = hist_r[e * 50 + lane];
        hmv = hist_m[e * 50 + lane];
    }
    int sa = 0, sk = 0;
    if (lane < 32) {
        sa = soc_a[e * 32 + lane];
        sk = soc_m[e * 32 + lane];
    }

    // ---- rating-embedding dim-quads (5 rows, f32), dims sub*4..+3 ----
    const float4* re4p = (const float4*)r_embed;
    const float4 re0 = re4p[0 * 16 + sub];
    const float4 re1 = re4p[1 * 16 + sub];
    const float4 re2 = re4p[2 * 16 + sub];
    const float4 re3 = re4p[3 * 16 + sub];
    const float4 re4 = re4p[4 * 16 + sub];

    // ---- ballots / counts ----
    uint64_t hb = __ballot(hmv != 0);
    const int hc = (int)__popcll(hb);
    int hrank = (int)__popcll(hb & ((1ull << lane) - 1));

    uint64_t sbm = __ballot(sk != 0);
    const int scn = (int)__popcll(sbm);
    int srank = (int)__popcll(sbm & ((1ull << lane) - 1));

    const float hw = 0.5f / (float)hc;     // hc >= 1 (mask[:,0]=True)
    const float sw = 0.5f / (float)scn;    // scn >= 1
    const int   n  = hc + scn;             // <= 82

    // ---- merged compaction: hist entries [0,hc), social [hc, n) ----
    // offsets are BYTE offsets into the f32 feature table (row = 256B)
    if (hmv) lcomp[wv][hrank] = hu << 8;
    if (sk)  lcomp[wv][hc + srank] = sa << 8;

    // ---- rating counts (replaces per-gather remb adds) ----
    const int c0 = (int)__popcll(__ballot(hmv && hr == 0));
    const int c1 = (int)__popcll(__ballot(hmv && hr == 1));
    const int c2 = (int)__popcll(__ballot(hmv && hr == 2));
    const int c3 = (int)__popcll(__ballot(hmv && hr == 3));
    const int c4 = (int)__popcll(__ballot(hmv && hr == 4));

    // ---- read back merged list into registers (wave-local) ----
    int pkA = lcomp[wv][lane];
    int pkB = lcomp[wv][64 + (lane & 31)];

    // ---- issue member-row loads (8 rows; 2 dwordx4 per lane) ----
    const int u0 = __shfl(nd, grp);
    const int u1 = __shfl(nd, 4 + grp);
    const float4 v0 = *(const float4*)(fB + ((unsigned)u0 << 8) + sub * 16);
    const float4 v1 = *(const float4*)(fB + ((unsigned)u1 << 8) + sub * 16);

    // ---- peel gather iter 0: 4 more loads in flight under the Q phase ----
    // entries idx = cbase+grp, cbase in {0,4,8,12}; weight from index.
    const int o0 = __shfl(pkA, 0  + grp);
    const int o1 = __shfl(pkA, 4  + grp);
    const int o2 = __shfl(pkA, 8  + grp);
    const int o3 = __shfl(pkA, 12 + grp);
    const float4 g0 = *(const float4*)(fB + (unsigned)o0 + sub * 16);
    const float4 g1 = *(const float4*)(fB + (unsigned)o1 + sub * 16);
    const float4 g2 = *(const float4*)(fB + (unsigned)o2 + sub * 16);
    const float4 g3 = *(const float4*)(fB + (unsigned)o3 + sub * 16);

    // ---- inline Q, two-pass through per-wave scratch (rows 0..3 then 4..7).
    //      lane (grp,sub): ATT dim k=sub, rows grp (pass1) / 4+grp (pass2).
    const float bg1v = bg1[sub];
    const float wk2  = wg2[sub];
    float h0 = bg1v, h1 = bg1v;

    *(float4*)&scratch[wv][grp * 68 + sub * 4] = v0;   // stage rows 0..3
    #pragma unroll
    for (int d4 = 0; d4 < 16; ++d4) {
        const float4 m  = *(const float4*)&scratch[wv][grp * 68 + d4 * 4];
        const float4 wk = *(const float4*)&wg1t[sub * 68 + d4 * 4];
        h0 += m.x * wk.x + m.y * wk.y + m.z * wk.z + m.w * wk.w;
    }
    *(float4*)&scratch[wv][grp * 68 + sub * 4] = v1;   // stage rows 4..7
    #pragma unroll
    for (int d4 = 0; d4 < 16; ++d4) {
        const float4 m  = *(const float4*)&scratch[wv][grp * 68 + d4 * 4];
        const float4 wk = *(const float4*)&wg1t[sub * 68 + d4 * 4];
        h1 += m.x * wk.x + m.y * wk.y + m.z * wk.z + m.w * wk.w;
    }

    // tanh (clamped, via exp) then * wg2[k], reduce over k (16 lanes/group)
    {
        float x0 = fminf(fmaxf(h0, -9.f), 9.f);
        float x1 = fminf(fmaxf(h1, -9.f), 9.f);
        float e20 = __expf(2.f * x0), e21 = __expf(2.f * x1);
        h0 = (e20 - 1.f) / (e20 + 1.f) * wk2;
        h1 = (e21 - 1.f) / (e21 + 1.f) * wk2;
        h0 += __shfl_xor(h0, 1); h1 += __shfl_xor(h1, 1);
        h0 += __shfl_xor(h0, 2); h1 += __shfl_xor(h1, 2);
        h0 += __shfl_xor(h0, 4); h1 += __shfl_xor(h1, 4);
        h0 += __shfl_xor(h0, 8); h1 += __shfl_xor(h1, 8);
    }
    const float bg2v = bg2[0];
    const float l0 = h0 + bg2v;          // logit of row grp   (uniform in group)
    const float l1 = h1 + bg2v;          // logit of row 4+grp

    // ---- softmax over the 8 member logits (4 groups x 2 rows) ----
    float mx = fmaxf(l0, l1);
    mx = fmaxf(mx, __shfl_xor(mx, 16));
    mx = fmaxf(mx, __shfl_xor(mx, 32));
    float e0 = __expf(l0 - mx), e1 = __expf(l1 - mx);
    float s = e0 + e1;
    s += __shfl_xor(s, 16);
    s += __shfl_xor(s, 32);
    const float a0 = e0 / s, a1 = e1 / s;

    // ---- attention-weighted member sum (rows still in v0/v1 regs) ----
    float4 sf4;
    sf4.x = a0 * v0.x + a1 * v1.x;
    sf4.y = a0 * v0.y + a1 * v1.y;
    sf4.z = a0 * v0.z + a1 * v1.z;
    sf4.w = a0 * v0.w + a1 * v1.w;

    // ---- consume peeled gather loads (weight from entry index) ----
    float4 nb4 = {0.f, 0.f, 0.f, 0.f};
    {
        const float w0 = (0  + grp < hc) ? hw : ((0  + grp < n) ? sw : 0.f);
        const float w1q= (4  + grp < hc) ? hw : ((4  + grp < n) ? sw : 0.f);
        const float w2 = (8  + grp < hc) ? hw : ((8  + grp < n) ? sw : 0.f);
        const float w3 = (12 + grp < hc) ? hw : ((12 + grp < n) ? sw : 0.f);
        nb4.x += w0 * g0.x + w1q * g1.x + w2 * g2.x + w3 * g3.x;
        nb4.y += w0 * g0.y + w1q * g1.y + w2 * g2.y + w3 * g3.y;
        nb4.z += w0 * g0.z + w1q * g1.z + w2 * g2.z + w3 * g3.z;
        nb4.w += w0 * g0.w + w1q * g1.w + w2 * g2.w + w3 * g3.w;
    }

    // ---- remaining merged gathers: 16 rows (4 independent loads) per iter ----
    for (int base = 16; base < n; base += 16) {
        #pragma unroll
        for (int j = 0; j < 4; ++j) {
            const int cbase = base + j * 4;       // uniform, 4-aligned
            int off;
            if (cbase < 64) off = __shfl(pkA, cbase + grp);
            else            off = __shfl(pkB, cbase - 64 + grp);
            const int idx = cbase + grp;
            const float w = (idx < hc) ? hw : ((idx < n) ? sw : 0.f);
            const float4 v = *(const float4*)(fB + (unsigned)off + sub * 16);
            nb4.x += w * v.x; nb4.y += w * v.y;
            nb4.z += w * v.z; nb4.w += w * v.w;
        }
    }

    // ---- cross-group reduction (sum row-slot partials; all lanes end equal) ----
#define XRED(v4)                                            \
    v4.x += __shfl_xor(v4.x, 16); v4.x += __shfl_xor(v4.x, 32); \
    v4.y += __shfl_xor(v4.y, 16); v4.y += __shfl_xor(v4.y, 32); \
    v4.z += __shfl_xor(v4.z, 16); v4.z += __shfl_xor(v4.z, 32); \
    v4.w += __shfl_xor(v4.w, 16); v4.w += __shfl_xor(v4.w, 32);
    XRED(sf4)
    XRED(nb4)
#undef XRED

    // ---- rating-count correction (scaled by 0.5/hc) ----
    float f0 = hw * (float)c0, f1 = hw * (float)c1, f2 = hw * (float)c2,
          f3 = hw * (float)c3, f4 = hw * (float)c4;
    nb4.x += f0 * re0.x + f1 * re1.x + f2 * re2.x + f3 * re3.x + f4 * re4.x;
    nb4.y += f0 * re0.y + f1 * re1.y + f2 * re2.y + f3 * re3.y + f4 * re4.y;
    nb4.z += f0 * re0.z + f1 * re1.z + f2 * re2.z + f3 * re3.z + f4 * re4.z;
    nb4.w += f0 * re0.w + f1 * re1.w + f2 * re2.w + f3 * re3.w + f4 * re4.w;

    // ---- park comb row in scratch (mrow is dead; wave-local, no barrier) ----
    if (grp == 0) *(float4*)&scratch[wv][sub * 4] = sf4;
    if (grp == 1) *(float4*)&scratch[wv][64 + sub * 4] = nb4;

    // ---- fused matvec: out[e][col] = relu(b1 + sum_k comb[k]*w1[k][col]) ----
    const int col = lane;
    float y = b1[col];
    #pragma unroll 8
    for (int k4 = 0; k4 < 32; ++k4) {
        const float4 c = *(const float4*)&scratch[wv][k4 * 4];
        y += c.x * w1[(k4 * 4 + 0) * 64 + col]
           + c.y * w1[(k4 * 4 + 1) * 64 + col]
           + c.z * w1[(k4 * 4 + 2) * 64 + col]
           + c.w * w1[(k4 * 4 + 3) * 64 + col];
    }
    out[(size_t)e * 64 + col] = fmaxf(y, 0.f);
}

extern "C" void kernel_launch(void* const* d_in, const int* in_sizes, int n_in,
                              void* d_out, int out_size, void* d_ws, size_t ws_size,
                              hipStream_t stream)
{
    const int*   nodes    = (const int*)d_in[0];
    const int*   hu       = (const int*)d_in[1];
    const int*   hr       = (const int*)d_in[2];
    const int*   hm       = (const int*)d_in[3];
    const int*   sa       = (const int*)d_in[4];
    const int*   smk      = (const int*)d_in[5];
    const float* features = (const float*)d_in[6];
    const float* r_embed  = (const float*)d_in[7];
    const float* wg1      = (const float*)d_in[8];
    const float* bg1      = (const float*)d_in[9];
    const float* wg2      = (const float*)d_in[10];
    const float* bg2      = (const float*)d_in[11];
    const float* w1       = (const float*)d_in[12];
    const float* b1       = (const float*)d_in[13];
    float* out = (float*)d_out;

    (void)d_ws; (void)ws_size;

    k_fused<<<BB / 4, 256, 0, stream>>>(nodes, hu, hr, hm, sa, smk,
                                        features, r_embed, wg1, bg1, wg2, bg2,
                                        w1, b1, out);
}

// Round 5
// 147.368 us; speedup vs baseline: 1.3407x; 1.3407x over previous
//
#include <hip/hip_runtime.h>
#include <cstdint>
#include <cstddef>

#define BB 16384

// ---------------- Single fully-fused kernel, low-LDS edition, NO VGPR cap.
// Round-4 lesson: __launch_bounds__(256,6) forced VGPR=40 -> massive spills
// (WRITE_SIZE 4MB->192MB, k_fused 52->110us). This build keeps the 10240B
// LDS footprint (-> 6 blocks/CU by LDS alone) but lets the allocator use its
// natural ~64 VGPRs (8 waves/SIMD allowed by HW -> LDS is the only binder).
__global__ __launch_bounds__(256) void k_fused(
    const int* __restrict__ nodes, const int* __restrict__ hist_u,
    const int* __restrict__ hist_r, const int* __restrict__ hist_m,
    const int* __restrict__ soc_a, const int* __restrict__ soc_m,
    const float* __restrict__ features, const float* __restrict__ r_embed,
    const float* __restrict__ wg1, const float* __restrict__ bg1,
    const float* __restrict__ wg2, const float* __restrict__ bg2,
    const float* __restrict__ w1, const float* __restrict__ b1,
    float* __restrict__ out)
{
    __shared__ float wg1t[16 * 68];      // 4352B: wg1 transposed [k][d], padded
    __shared__ int   lcomp[4][96];       // 1536B: merged byte-offset list per wave
    __shared__ float scratch[4][272];    // 4352B: per-wave union:
                                         //   phase Q   : mrow[4 rows][68]
                                         //   phase out : combs[128]
    // total LDS = 10240B -> 6 blocks/CU under a 64KB budget

    const int tid  = threadIdx.x;
    const int lane = tid & 63;
    const int wv   = tid >> 6;
    const int e    = blockIdx.x * 4 + wv;
    const int sub  = lane & 15;
    const int grp  = lane >> 4;
    const char* fB = (const char*)features;

    // ---- stage wg1 transposed (block-shared), then the ONLY barrier ----
    {
        const float4 w = ((const float4*)wg1)[tid];   // wg1[64][16]: d=tid>>2, k0=(tid&3)*4
        const int d = tid >> 2, k0 = (tid & 3) * 4;
        wg1t[(k0 + 0) * 68 + d] = w.x;
        wg1t[(k0 + 1) * 68 + d] = w.y;
        wg1t[(k0 + 2) * 68 + d] = w.z;
        wg1t[(k0 + 3) * 68 + d] = w.w;
    }
    __syncthreads();   // before any gather issue: barrier drain costs nothing

    // ---- zero-init merged list (tail entries: offset 0 = row 0) ----
    lcomp[wv][lane] = 0;
    if (lane < 32) lcomp[wv][64 + lane] = 0;

    // ---- index loads (issue ASAP) ----
    int nd = (lane < 8) ? nodes[e * 8 + lane] : 0;
    int hu = 0, hr = 0, hmv = 0;
    if (lane < 50) {
        hu  = hist_u[e * 50 + lane];
        hr  = hist_r[e * 50 + lane];
        hmv = hist_m[e * 50 + lane];
    }
    int sa = 0, sk = 0;
    if (lane < 32) {
        sa = soc_a[e * 32 + lane];
        sk = soc_m[e * 32 + lane];
    }

    // ---- rating-embedding dim-quads (5 rows, f32), dims sub*4..+3 ----
    const float4* re4p = (const float4*)r_embed;
    const float4 re0 = re4p[0 * 16 + sub];
    const float4 re1 = re4p[1 * 16 + sub];
    const float4 re2 = re4p[2 * 16 + sub];
    const float4 re3 = re4p[3 * 16 + sub];
    const float4 re4 = re4p[4 * 16 + sub];

    // ---- ballots / counts ----
    uint64_t hb = __ballot(hmv != 0);
    const int hc = (int)__popcll(hb);
    int hrank = (int)__popcll(hb & ((1ull << lane) - 1));

    uint64_t sbm = __ballot(sk != 0);
    const int scn = (int)__popcll(sbm);
    int srank = (int)__popcll(sbm & ((1ull << lane) - 1));

    const float hw = 0.5f / (float)hc;     // hc >= 1 (mask[:,0]=True)
    const float sw = 0.5f / (float)scn;    // scn >= 1
    const int   n  = hc + scn;             // <= 82

    // ---- merged compaction: hist entries [0,hc), social [hc, n) ----
    // offsets are BYTE offsets into the f32 feature table (row = 256B)
    if (hmv) lcomp[wv][hrank] = hu << 8;
    if (sk)  lcomp[wv][hc + srank] = sa << 8;

    // ---- rating counts (replaces per-gather remb adds) ----
    const int c0 = (int)__popcll(__ballot(hmv && hr == 0));
    const int c1 = (int)__popcll(__ballot(hmv && hr == 1));
    const int c2 = (int)__popcll(__ballot(hmv && hr == 2));
    const int c3 = (int)__popcll(__ballot(hmv && hr == 3));
    const int c4 = (int)__popcll(__ballot(hmv && hr == 4));

    // ---- read back merged list into registers (wave-local) ----
    int pkA = lcomp[wv][lane];
    int pkB = lcomp[wv][64 + (lane & 31)];

    // ---- issue member-row loads (8 rows; 2 dwordx4 per lane) ----
    const int u0 = __shfl(nd, grp);
    const int u1 = __shfl(nd, 4 + grp);
    const float4 v0 = *(const float4*)(fB + ((unsigned)u0 << 8) + sub * 16);
    const float4 v1 = *(const float4*)(fB + ((unsigned)u1 << 8) + sub * 16);

    // ---- peel gather iter 0: 4 more loads in flight under the Q phase ----
    // entries idx = cbase+grp, cbase in {0,4,8,12}; weight from index.
    const int o0 = __shfl(pkA, 0  + grp);
    const int o1 = __shfl(pkA, 4  + grp);
    const int o2 = __shfl(pkA, 8  + grp);
    const int o3 = __shfl(pkA, 12 + grp);
    const float4 g0 = *(const float4*)(fB + (unsigned)o0 + sub * 16);
    const float4 g1 = *(const float4*)(fB + (unsigned)o1 + sub * 16);
    const float4 g2 = *(const float4*)(fB + (unsigned)o2 + sub * 16);
    const float4 g3 = *(const float4*)(fB + (unsigned)o3 + sub * 16);

    // ---- inline Q, two-pass through per-wave scratch (rows 0..3 then 4..7).
    //      lane (grp,sub): ATT dim k=sub, rows grp (pass1) / 4+grp (pass2).
    const float bg1v = bg1[sub];
    const float wk2  = wg2[sub];
    float h0 = bg1v, h1 = bg1v;

    *(float4*)&scratch[wv][grp * 68 + sub * 4] = v0;   // stage rows 0..3
    #pragma unroll
    for (int d4 = 0; d4 < 16; ++d4) {
        const float4 m  = *(const float4*)&scratch[wv][grp * 68 + d4 * 4];
        const float4 wk = *(const float4*)&wg1t[sub * 68 + d4 * 4];
        h0 += m.x * wk.x + m.y * wk.y + m.z * wk.z + m.w * wk.w;
    }
    *(float4*)&scratch[wv][grp * 68 + sub * 4] = v1;   // stage rows 4..7
    #pragma unroll
    for (int d4 = 0; d4 < 16; ++d4) {
        const float4 m  = *(const float4*)&scratch[wv][grp * 68 + d4 * 4];
        const float4 wk = *(const float4*)&wg1t[sub * 68 + d4 * 4];
        h1 += m.x * wk.x + m.y * wk.y + m.z * wk.z + m.w * wk.w;
    }

    // tanh (clamped, via exp) then * wg2[k], reduce over k (16 lanes/group)
    {
        float x0 = fminf(fmaxf(h0, -9.f), 9.f);
        float x1 = fminf(fmaxf(h1, -9.f), 9.f);
        float e20 = __expf(2.f * x0), e21 = __expf(2.f * x1);
        h0 = (e20 - 1.f) / (e20 + 1.f) * wk2;
        h1 = (e21 - 1.f) / (e21 + 1.f) * wk2;
        h0 += __shfl_xor(h0, 1); h1 += __shfl_xor(h1, 1);
        h0 += __shfl_xor(h0, 2); h1 += __shfl_xor(h1, 2);
        h0 += __shfl_xor(h0, 4); h1 += __shfl_xor(h1, 4);
        h0 += __shfl_xor(h0, 8); h1 += __shfl_xor(h1, 8);
    }
    const float bg2v = bg2[0];
    const float l0 = h0 + bg2v;          // logit of row grp   (uniform in group)
    const float l1 = h1 + bg2v;          // logit of row 4+grp

    // ---- softmax over the 8 member logits (4 groups x 2 rows) ----
    float mx = fmaxf(l0, l1);
    mx = fmaxf(mx, __shfl_xor(mx, 16));
    mx = fmaxf(mx, __shfl_xor(mx, 32));
    float e0 = __expf(l0 - mx), e1 = __expf(l1 - mx);
    float s = e0 + e1;
    s += __shfl_xor(s, 16);
    s += __shfl_xor(s, 32);
    const float a0 = e0 / s, a1 = e1 / s;

    // ---- attention-weighted member sum (rows still in v0/v1 regs) ----
    float4 sf4;
    sf4.x = a0 * v0.x + a1 * v1.x;
    sf4.y = a0 * v0.y + a1 * v1.y;
    sf4.z = a0 * v0.z + a1 * v1.z;
    sf4.w = a0 * v0.w + a1 * v1.w;

    // ---- consume peeled gather loads (weight from entry index) ----
    float4 nb4 = {0.f, 0.f, 0.f, 0.f};
    {
        const float w0 = (0  + grp < hc) ? hw : ((0  + grp < n) ? sw : 0.f);
        const float w1q= (4  + grp < hc) ? hw : ((4  + grp < n) ? sw : 0.f);
        const float w2 = (8  + grp < hc) ? hw : ((8  + grp < n) ? sw : 0.f);
        const float w3 = (12 + grp < hc) ? hw : ((12 + grp < n) ? sw : 0.f);
        nb4.x += w0 * g0.x + w1q * g1.x + w2 * g2.x + w3 * g3.x;
        nb4.y += w0 * g0.y + w1q * g1.y + w2 * g2.y + w3 * g3.y;
        nb4.z += w0 * g0.z + w1q * g1.z + w2 * g2.z + w3 * g3.z;
        nb4.w += w0 * g0.w + w1q * g1.w + w2 * g2.w + w3 * g3.w;
    }

    // ---- remaining merged gathers: 16 rows (4 independent loads) per iter ----
    for (int base = 16; base < n; base += 16) {
        #pragma unroll
        for (int j = 0; j < 4; ++j) {
            const int cbase = base + j * 4;       // uniform, 4-aligned
            int off;
            if (cbase < 64) off = __shfl(pkA, cbase + grp);
            else            off = __shfl(pkB, cbase - 64 + grp);
            const int idx = cbase + grp;
            const float w = (idx < hc) ? hw : ((idx < n) ? sw : 0.f);
            const float4 v = *(const float4*)(fB + (unsigned)off + sub * 16);
            nb4.x += w * v.x; nb4.y += w * v.y;
            nb4.z += w * v.z; nb4.w += w * v.w;
        }
    }

    // ---- cross-group reduction (sum row-slot partials; all lanes end equal) ----
#define XRED(v4)                                            \
    v4.x += __shfl_xor(v4.x, 16); v4.x += __shfl_xor(v4.x, 32); \
    v4.y += __shfl_xor(v4.y, 16); v4.y += __shfl_xor(v4.y, 32); \
    v4.z += __shfl_xor(v4.z, 16); v4.z += __shfl_xor(v4.z, 32); \
    v4.w += __shfl_xor(v4.w, 16); v4.w += __shfl_xor(v4.w, 32);
    XRED(sf4)
    XRED(nb4)
#undef XRED

    // ---- rating-count correction (scaled by 0.5/hc) ----
    float f0 = hw * (float)c0, f1 = hw * (float)c1, f2 = hw * (float)c2,
          f3 = hw * (float)c3, f4 = hw * (float)c4;
    nb4.x += f0 * re0.x + f1 * re1.x + f2 * re2.x + f3 * re3.x + f4 * re4.x;
    nb4.y += f0 * re0.y + f1 * re1.y + f2 * re2.y + f3 * re3.y + f4 * re4.y;
    nb4.z += f0 * re0.z + f1 * re1.z + f2 * re2.z + f3 * re3.z + f4 * re4.z;
    nb4.w += f0 * re0.w + f1 * re1.w + f2 * re2.w + f3 * re3.w + f4 * re4.w;

    // ---- park comb row in scratch (mrow is dead; wave-local, no barrier) ----
    if (grp == 0) *(float4*)&scratch[wv][sub * 4] = sf4;
    if (grp == 1) *(float4*)&scratch[wv][64 + sub * 4] = nb4;

    // ---- fused matvec: out[e][col] = relu(b1 + sum_k comb[k]*w1[k][col]) ----
    const int col = lane;
    float y = b1[col];
    #pragma unroll 8
    for (int k4 = 0; k4 < 32; ++k4) {
        const float4 c = *(const float4*)&scratch[wv][k4 * 4];
        y += c.x * w1[(k4 * 4 + 0) * 64 + col]
           + c.y * w1[(k4 * 4 + 1) * 64 + col]
           + c.z * w1[(k4 * 4 + 2) * 64 + col]
           + c.w * w1[(k4 * 4 + 3) * 64 + col];
    }
    out[(size_t)e * 64 + col] = fmaxf(y, 0.f);
}

extern "C" void kernel_launch(void* const* d_in, const int* in_sizes, int n_in,
                              void* d_out, int out_size, void* d_ws, size_t ws_size,
                              hipStream_t stream)
{
    const int*   nodes    = (const int*)d_in[0];
    const int*   hu       = (const int*)d_in[1];
    const int*   hr       = (const int*)d_in[2];
    const int*   hm       = (const int*)d_in[3];
    const int*   sa       = (const int*)d_in[4];
    const int*   smk      = (const int*)d_in[5];
    const float* features = (const float*)d_in[6];
    const float* r_embed  = (const float*)d_in[7];
    const float* wg1      = (const float*)d_in[8];
    const float* bg1      = (const float*)d_in[9];
    const float* wg2      = (const float*)d_in[10];
    const float* bg2      = (const float*)d_in[11];
    const float* w1       = (const float*)d_in[12];
    const float* b1       = (const float*)d_in[13];
    float* out = (float*)d_out;

    (void)d_ws; (void)ws_size;

    k_fused<<<BB / 4, 256, 0, stream>>>(nodes, hu, hr, hm, sa, smk,
                                        features, r_embed, wg1, bg1, wg2, bg2,
                                        w1, b1, out);
}

// Round 6
// 139.646 us; speedup vs baseline: 1.4149x; 1.0553x over previous
//
#include <hip/hip_runtime.h>
#include <cstdint>
#include <cstddef>

#define BB 16384

// ---------------- Single fully-fused kernel — round-2 structure + LDS alias.
// Round-5 lessons: (a) VGPR 84 crossed the 64-reg occupancy step; (b) the
// two-pass scratch staging cost 2.75M bank-conflict cycles. Revert to the
// single-pass 8-row mrow (round-2 pattern, 131K conflicts, VGPR 64) and cut
// LDS by ALIASING instead of restructuring:
//   mrow region per wave (544 floats) serves, in strictly ordered wave-local
//   lifetimes: lcomp int[96] -> member rows [8][68] -> comb[128].
// LDS = 4352 (wg1t) + 8704 (mrow) = 13056 -> 13312 alloc -> 4 blocks/CU
// (16 waves, cap holds for any VGPR <= 128, so the peeled gather prefetch is
// register-free). Matvec rewritten to float4 w1 loads: 32 VMEM/wave vs 128.
__global__ __launch_bounds__(256) void k_fused(
    const int* __restrict__ nodes, const int* __restrict__ hist_u,
    const int* __restrict__ hist_r, const int* __restrict__ hist_m,
    const int* __restrict__ soc_a, const int* __restrict__ soc_m,
    const float* __restrict__ features, const float* __restrict__ r_embed,
    const float* __restrict__ wg1, const float* __restrict__ bg1,
    const float* __restrict__ wg2, const float* __restrict__ bg2,
    const float* __restrict__ w1, const float* __restrict__ b1,
    float* __restrict__ out)
{
    __shared__ float wg1t[16 * 68];      // 4352B: wg1 transposed [k][d], padded
    __shared__ float mrow[4][8 * 68];    // 8704B per-wave union (see header)

    const int tid  = threadIdx.x;
    const int lane = tid & 63;
    const int wv   = tid >> 6;
    const int e    = blockIdx.x * 4 + wv;
    const int sub  = lane & 15;
    const int grp  = lane >> 4;
    const char* fB = (const char*)features;

    int*   lc = (int*)&mrow[wv][0];      // lifetime 1: merged offset list [96]
    float* cb = &mrow[wv][0];            // lifetime 3: comb row [128]

    // ---- stage wg1 transposed (block-shared) ----
    {
        const float4 w = ((const float4*)wg1)[tid];   // wg1[64][16]: d=tid>>2, k0=(tid&3)*4
        const int d = tid >> 2, k0 = (tid & 3) * 4;
        wg1t[(k0 + 0) * 68 + d] = w.x;
        wg1t[(k0 + 1) * 68 + d] = w.y;
        wg1t[(k0 + 2) * 68 + d] = w.z;
        wg1t[(k0 + 3) * 68 + d] = w.w;
    }

    // ---- zero-init merged list (tail entries: offset 0 = row 0) ----
    lc[lane] = 0;
    if (lane < 32) lc[64 + lane] = 0;

    // ---- index loads (issue ASAP) ----
    int nd = (lane < 8) ? nodes[e * 8 + lane] : 0;
    int hu = 0, hr = 0, hmv = 0;
    if (lane < 50) {
        hu  = hist_u[e * 50 + lane];
        hr  = hist_r[e * 50 + lane];
        hmv = hist_m[e * 50 + lane];
    }
    int sa = 0, sk = 0;
    if (lane < 32) {
        sa = soc_a[e * 32 + lane];
        sk = soc_m[e * 32 + lane];
    }

    // ---- ballots / counts ----
    uint64_t hb = __ballot(hmv != 0);
    const int hc = (int)__popcll(hb);
    int hrank = (int)__popcll(hb & ((1ull << lane) - 1));

    uint64_t sbm = __ballot(sk != 0);
    const int scn = (int)__popcll(sbm);
    int srank = (int)__popcll(sbm & ((1ull << lane) - 1));

    const float hw = 0.5f / (float)hc;     // hc >= 1 (mask[:,0]=True)
    const float sw = 0.5f / (float)scn;    // scn >= 1
    const int   n  = hc + scn;             // <= 82

    // ---- merged compaction: hist entries [0,hc), social [hc, n) ----
    // offsets are BYTE offsets into the f32 feature table (row = 256B)
    if (hmv) lc[hrank] = hu << 8;
    if (sk)  lc[hc + srank] = sa << 8;

    // ---- rating counts (replaces per-gather remb adds) ----
    const int c0 = (int)__popcll(__ballot(hmv && hr == 0));
    const int c1 = (int)__popcll(__ballot(hmv && hr == 1));
    const int c2 = (int)__popcll(__ballot(hmv && hr == 2));
    const int c3 = (int)__popcll(__ballot(hmv && hr == 3));
    const int c4 = (int)__popcll(__ballot(hmv && hr == 4));

    // ---- read back merged list (ends lcomp lifetime) ----
    int pkA = lc[lane];
    int pkB = lc[64 + (lane & 31)];

    // ---- member-row gathers (8 rows; 2 dwordx4 per lane) ----
    const int u0 = __shfl(nd, grp);
    const int u1 = __shfl(nd, 4 + grp);
    const float4 v0 = *(const float4*)(fB + ((unsigned)u0 << 8) + sub * 16);
    const float4 v1 = *(const float4*)(fB + ((unsigned)u1 << 8) + sub * 16);

    // ---- peel gather iter 0: 4 loads in flight under the Q phase ----
    const int o0 = __shfl(pkA, 0  + grp);
    const int o1 = __shfl(pkA, 4  + grp);
    const int o2 = __shfl(pkA, 8  + grp);
    const int o3 = __shfl(pkA, 12 + grp);
    const float4 g0 = *(const float4*)(fB + (unsigned)o0 + sub * 16);
    const float4 g1 = *(const float4*)(fB + (unsigned)o1 + sub * 16);
    const float4 g2 = *(const float4*)(fB + (unsigned)o2 + sub * 16);
    const float4 g3 = *(const float4*)(fB + (unsigned)o3 + sub * 16);

    // ---- stage member rows (single pass, round-2 low-conflict pattern) ----
    *(float4*)&mrow[wv][grp * 68 + sub * 4]       = v0;
    *(float4*)&mrow[wv][(4 + grp) * 68 + sub * 4] = v1;

    __syncthreads();   // wg1t visible; also drains the mrow writes

    // ---- inline Q: lane (grp,sub) owns ATT dim k=sub, rows grp and 4+grp ----
    float h0, h1;
    {
        const float bk = bg1[sub];
        h0 = bk; h1 = bk;
        #pragma unroll
        for (int d4 = 0; d4 < 16; ++d4) {
            const float4 wk = *(const float4*)&wg1t[sub * 68 + d4 * 4];
            const float4 m0 = *(const float4*)&mrow[wv][grp * 68 + d4 * 4];
            const float4 m1 = *(const float4*)&mrow[wv][(4 + grp) * 68 + d4 * 4];
            h0 += m0.x * wk.x + m0.y * wk.y + m0.z * wk.z + m0.w * wk.w;
            h1 += m1.x * wk.x + m1.y * wk.y + m1.z * wk.z + m1.w * wk.w;
        }
        const float wk2 = wg2[sub];
        float x0 = fminf(fmaxf(h0, -9.f), 9.f);
        float x1 = fminf(fmaxf(h1, -9.f), 9.f);
        float e20 = __expf(2.f * x0), e21 = __expf(2.f * x1);
        h0 = (e20 - 1.f) / (e20 + 1.f) * wk2;
        h1 = (e21 - 1.f) / (e21 + 1.f) * wk2;
        h0 += __shfl_xor(h0, 1); h1 += __shfl_xor(h1, 1);
        h0 += __shfl_xor(h0, 2); h1 += __shfl_xor(h1, 2);
        h0 += __shfl_xor(h0, 4); h1 += __shfl_xor(h1, 4);
        h0 += __shfl_xor(h0, 8); h1 += __shfl_xor(h1, 8);
    }
    const float bg2v = bg2[0];
    const float l0 = h0 + bg2v;          // logit of row grp   (uniform in group)
    const float l1 = h1 + bg2v;          // logit of row 4+grp

    // ---- softmax over the 8 member logits (4 groups x 2 rows) ----
    float mx = fmaxf(l0, l1);
    mx = fmaxf(mx, __shfl_xor(mx, 16));
    mx = fmaxf(mx, __shfl_xor(mx, 32));
    float e0 = __expf(l0 - mx), e1 = __expf(l1 - mx);
    float s = e0 + e1;
    s += __shfl_xor(s, 16);
    s += __shfl_xor(s, 32);
    const float a0 = e0 / s, a1 = e1 / s;

    // ---- attention-weighted member sum (rows still in v0/v1 regs) ----
    float4 sf4;
    sf4.x = a0 * v0.x + a1 * v1.x;
    sf4.y = a0 * v0.y + a1 * v1.y;
    sf4.z = a0 * v0.z + a1 * v1.z;
    sf4.w = a0 * v0.w + a1 * v1.w;

    // ---- consume peeled gather loads (weight from entry index) ----
    float4 nb4 = {0.f, 0.f, 0.f, 0.f};
    {
        const float w0 = (0  + grp < hc) ? hw : ((0  + grp < n) ? sw : 0.f);
        const float w1q= (4  + grp < hc) ? hw : ((4  + grp < n) ? sw : 0.f);
        const float w2 = (8  + grp < hc) ? hw : ((8  + grp < n) ? sw : 0.f);
        const float w3 = (12 + grp < hc) ? hw : ((12 + grp < n) ? sw : 0.f);
        nb4.x += w0 * g0.x + w1q * g1.x + w2 * g2.x + w3 * g3.x;
        nb4.y += w0 * g0.y + w1q * g1.y + w2 * g2.y + w3 * g3.y;
        nb4.z += w0 * g0.z + w1q * g1.z + w2 * g2.z + w3 * g3.z;
        nb4.w += w0 * g0.w + w1q * g1.w + w2 * g2.w + w3 * g3.w;
    }

    // ---- remaining merged gathers: 16 rows (4 independent loads) per iter ----
    for (int base = 16; base < n; base += 16) {
        #pragma unroll
        for (int j = 0; j < 4; ++j) {
            const int cbase = base + j * 4;       // uniform, 4-aligned
            int off;
            if (cbase < 64) off = __shfl(pkA, cbase + grp);
            else            off = __shfl(pkB, cbase - 64 + grp);
            const int idx = cbase + grp;
            const float w = (idx < hc) ? hw : ((idx < n) ? sw : 0.f);
            const float4 v = *(const float4*)(fB + (unsigned)off + sub * 16);
            nb4.x += w * v.x; nb4.y += w * v.y;
            nb4.z += w * v.z; nb4.w += w * v.w;
        }
    }

    // ---- cross-group reduction (sum row-slot partials; all lanes end equal) ----
#define XRED(v4)                                            \
    v4.x += __shfl_xor(v4.x, 16); v4.x += __shfl_xor(v4.x, 32); \
    v4.y += __shfl_xor(v4.y, 16); v4.y += __shfl_xor(v4.y, 32); \
    v4.z += __shfl_xor(v4.z, 16); v4.z += __shfl_xor(v4.z, 32); \
    v4.w += __shfl_xor(v4.w, 16); v4.w += __shfl_xor(v4.w, 32);
    XRED(sf4)
    XRED(nb4)
#undef XRED

    // ---- rating-count correction (scaled by 0.5/hc); re loads late to
    //      keep mid-kernel register pressure down ----
    {
        const float4* re4p = (const float4*)r_embed;
        const float4 re0 = re4p[0 * 16 + sub];
        const float4 re1 = re4p[1 * 16 + sub];
        const float4 re2 = re4p[2 * 16 + sub];
        const float4 re3 = re4p[3 * 16 + sub];
        const float4 re4 = re4p[4 * 16 + sub];
        float f0 = hw * (float)c0, f1 = hw * (float)c1, f2 = hw * (float)c2,
              f3 = hw * (float)c3, f4 = hw * (float)c4;
        nb4.x += f0 * re0.x + f1 * re1.x + f2 * re2.x + f3 * re3.x + f4 * re4.x;
        nb4.y += f0 * re0.y + f1 * re1.y + f2 * re2.y + f3 * re3.y + f4 * re4.y;
        nb4.z += f0 * re0.z + f1 * re1.z + f2 * re2.z + f3 * re3.z + f4 * re4.z;
        nb4.w += f0 * re0.w + f1 * re1.w + f2 * re2.w + f3 * re3.w + f4 * re4.w;
    }

    // ---- park comb row (mrow dead after Q; wave-local, no barrier) ----
    if (grp == 0) *(float4*)&cb[sub * 4] = sf4;
    if (grp == 1) *(float4*)&cb[64 + sub * 4] = nb4;

    // ---- fused matvec, float4 w1 loads (32 VMEM/wave instead of 128):
    //      lane (grp,sub) accumulates cols 4sub..4sub+3 over k = 4j+grp.
    //      Each instr covers 4 w1 rows = contiguous 1KB, L1-resident. ----
    float4 p = {0.f, 0.f, 0.f, 0.f};
    #pragma unroll 8
    for (int j = 0; j < 32; ++j) {
        const float  c  = cb[j * 4 + grp];                     // LDS broadcast
        const float4 wv4 = *(const float4*)(w1 + (j * 4 + grp) * 64 + sub * 4);
        p.x += c * wv4.x;
        p.y += c * wv4.y;
        p.z += c * wv4.z;
        p.w += c * wv4.w;
    }
    // reduce the 4 k-residue partials across grp lanes
    p.x += __shfl_xor(p.x, 16); p.x += __shfl_xor(p.x, 32);
    p.y += __shfl_xor(p.y, 16); p.y += __shfl_xor(p.y, 32);
    p.z += __shfl_xor(p.z, 16); p.z += __shfl_xor(p.z, 32);
    p.w += __shfl_xor(p.w, 16); p.w += __shfl_xor(p.w, 32);
    if (grp == 0) {
        const float4 bv = *(const float4*)(b1 + sub * 4);
        float4 o;
        o.x = fmaxf(p.x + bv.x, 0.f);
        o.y = fmaxf(p.y + bv.y, 0.f);
        o.z = fmaxf(p.z + bv.z, 0.f);
        o.w = fmaxf(p.w + bv.w, 0.f);
        *(float4*)(out + (size_t)e * 64 + sub * 4) = o;
    }
}

extern "C" void kernel_launch(void* const* d_in, const int* in_sizes, int n_in,
                              void* d_out, int out_size, void* d_ws, size_t ws_size,
                              hipStream_t stream)
{
    const int*   nodes    = (const int*)d_in[0];
    const int*   hu       = (const int*)d_in[1];
    const int*   hr       = (const int*)d_in[2];
    const int*   hm       = (const int*)d_in[3];
    const int*   sa       = (const int*)d_in[4];
    const int*   smk      = (const int*)d_in[5];
    const float* features = (const float*)d_in[6];
    const float* r_embed  = (const float*)d_in[7];
    const float* wg1      = (const float*)d_in[8];
    const float* bg1      = (const float*)d_in[9];
    const float* wg2      = (const float*)d_in[10];
    const float* bg2      = (const float*)d_in[11];
    const float* w1       = (const float*)d_in[12];
    const float* b1       = (const float*)d_in[13];
    float* out = (float*)d_out;

    (void)d_ws; (void)ws_size;

    k_fused<<<BB / 4, 256, 0, stream>>>(nodes, hu, hr, hm, sa, smk,
                                        features, r_embed, wg1, bg1, wg2, bg2,
                                        w1, b1, out);
}

// Round 7
// 138.537 us; speedup vs baseline: 1.4262x; 1.0080x over previous
//
#include <hip/hip_runtime.h>
#include <cstdint>
#include <cstddef>

#define NUSERS 100000
#define BB 16384

static __device__ __forceinline__ unsigned short f2bf(float x) {
    unsigned u = __float_as_uint(x);
    u += 0x7FFF + ((u >> 16) & 1);          // round-to-nearest-even
    return (unsigned short)(u >> 16);
}
static __device__ __forceinline__ float4 bf4_to_f4(ushort4 h) {
    float4 r;
    r.x = __uint_as_float((unsigned)h.x << 16);
    r.y = __uint_as_float((unsigned)h.y << 16);
    r.z = __uint_as_float((unsigned)h.z << 16);
    r.w = __uint_as_float((unsigned)h.w << 16);
    return r;
}

// ---------------- K0: per-user attention score Q[u] AND bf16 feature table.
// Round-2 proved the workspace re-poison fills are UNCONDITIONAL, so using
// d_ws is free. Streaming kernel: 25.6MB read + 12.8MB+0.4MB write ~ 7us.
__global__ __launch_bounds__(256) void k0_scores(
    const float* __restrict__ features, const float* __restrict__ wg1,
    const float* __restrict__ bg1, const float* __restrict__ wg2,
    const float* __restrict__ bg2, float* __restrict__ Q,
    unsigned short* __restrict__ fbf)
{
    __shared__ float frow[16 * 68];   // 16 user rows, padded
    __shared__ float wg1t[16 * 68];   // wg1 transposed [k][d], padded
    const int tid = threadIdx.x;
    const int blk = blockIdx.x;

    // one float4 per thread covers the block's 16 rows x 64 dims
    const float4 v = ((const float4*)(features + (size_t)blk * 1024))[tid];
    {
        const int row = tid >> 4, q = tid & 15;     // row-major quads
        *(float4*)&frow[row * 68 + q * 4] = v;
    }
    {
        const float4 w = ((const float4*)wg1)[tid]; // wg1[64][16]: d=tid>>2, k0=(tid&3)*4
        const int d = tid >> 2, k0 = (tid & 3) * 4;
        wg1t[(k0 + 0) * 68 + d] = w.x;
        wg1t[(k0 + 1) * 68 + d] = w.y;
        wg1t[(k0 + 2) * 68 + d] = w.z;
        wg1t[(k0 + 3) * 68 + d] = w.w;
    }
    // bf16 table emit (coalesced 8B/lane), from registers
    {
        ushort4 o;
        o.x = f2bf(v.x); o.y = f2bf(v.y); o.z = f2bf(v.z); o.w = f2bf(v.w);
        *(ushort4*)(fbf + (size_t)blk * 1024 + tid * 4) = o;
    }
    __syncthreads();

    const int k = tid & 15, ul = tid >> 4;
    float x = bg1[k];
    #pragma unroll
    for (int d4 = 0; d4 < 16; ++d4) {
        const float4 f  = *(const float4*)&frow[ul * 68 + d4 * 4];
        const float4 wv = *(const float4*)&wg1t[k * 68 + d4 * 4];
        x += f.x * wv.x + f.y * wv.y + f.z * wv.z + f.w * wv.w;
    }
    float xx = fminf(fmaxf(x, -9.f), 9.f);
    float e2 = __expf(2.f * xx);
    float th = (e2 - 1.f) / (e2 + 1.f);
    float t = th * wg2[k];
    t += __shfl_xor(t, 1);
    t += __shfl_xor(t, 2);
    t += __shfl_xor(t, 4);
    t += __shfl_xor(t, 8);
    if (k == 0) Q[blk * 16 + ul] = t + bg2[0];
}

// ---------------- K1: lean gather kernel against the bf16 table.
// Round-6 counters: duration tracked beyond-L2 bytes at ~2.1 TB/s effective
// (random 256B rows over a 25.6MB table >> 4MB L2). This version halves row
// bytes (128B) and halves the table footprint (12.8MB -> ~2x L2 hit rate),
// and removes the inline-Q phase entirely (Q precomputed in K0):
//  - no wg1t / mrow staging, no __syncthreads, LDS = 2KB (aliased lcomp/comb)
//  - float4 w1 matvec (32 VMEM/wave) with cross-grp reduce (round-6 pattern)
__global__ __launch_bounds__(256) void k1_fuse(
    const int* __restrict__ nodes, const int* __restrict__ hist_u,
    const int* __restrict__ hist_r, const int* __restrict__ hist_m,
    const int* __restrict__ soc_a, const int* __restrict__ soc_m,
    const unsigned short* __restrict__ fbf, const float* __restrict__ r_embed,
    const float* __restrict__ Q, const float* __restrict__ w1,
    const float* __restrict__ b1, float* __restrict__ out)
{
    __shared__ float wvbuf[4][128];   // 2048B: per-wave union
                                      //   lifetime 1: lcomp int[96]
                                      //   lifetime 2: comb  float[128]

    const int tid  = threadIdx.x;
    const int lane = tid & 63;
    const int wv   = tid >> 6;
    const int e    = blockIdx.x * 4 + wv;
    const int sub  = lane & 15;
    const int grp  = lane >> 4;
    const char* fb = (const char*)fbf;

    int*   lc = (int*)&wvbuf[wv][0];
    float* cb = &wvbuf[wv][0];

    // ---- zero-init merged list (tail entries: offset 0 = row 0) ----
    lc[lane] = 0;
    if (lane < 32) lc[64 + lane] = 0;

    // ---- index loads (issue ASAP) ----
    int nd = (lane < 8) ? nodes[e * 8 + lane] : 0;
    int hu = 0, hr = 0, hmv = 0;
    if (lane < 50) {
        hu  = hist_u[e * 50 + lane];
        hr  = hist_r[e * 50 + lane];
        hmv = hist_m[e * 50 + lane];
    }
    int sa = 0, sk = 0;
    if (lane < 32) {
        sa = soc_a[e * 32 + lane];
        sk = soc_m[e * 32 + lane];
    }

    // ---- ballots / counts ----
    uint64_t hb = __ballot(hmv != 0);
    const int hc = (int)__popcll(hb);
    int hrank = (int)__popcll(hb & ((1ull << lane) - 1));

    uint64_t sbm = __ballot(sk != 0);
    const int scn = (int)__popcll(sbm);
    int srank = (int)__popcll(sbm & ((1ull << lane) - 1));

    const float hw = 0.5f / (float)hc;     // hc >= 1 (mask[:,0]=True)
    const float sw = 0.5f / (float)scn;    // scn >= 1
    const int   n  = hc + scn;             // <= 82

    // ---- merged compaction: hist entries [0,hc), social [hc, n) ----
    // offsets are BYTE offsets into the bf16 table (row = 128B)
    if (hmv) lc[hrank] = hu << 7;
    if (sk)  lc[hc + srank] = sa << 7;

    // ---- rating counts (replaces per-gather remb adds) ----
    const int c0 = (int)__popcll(__ballot(hmv && hr == 0));
    const int c1 = (int)__popcll(__ballot(hmv && hr == 1));
    const int c2 = (int)__popcll(__ballot(hmv && hr == 2));
    const int c3 = (int)__popcll(__ballot(hmv && hr == 3));
    const int c4 = (int)__popcll(__ballot(hmv && hr == 4));

    // ---- read back merged list (ends lcomp lifetime) ----
    int pkA = lc[lane];
    int pkB = lc[64 + (lane & 31)];

    // ---- softmax over 8 group logits from precomputed Q (lanes 0..7) ----
    float sc = (lane < 8) ? Q[nd] : -1e30f;
    float mx = sc;
    mx = fmaxf(mx, __shfl_xor(mx, 1));
    mx = fmaxf(mx, __shfl_xor(mx, 2));
    mx = fmaxf(mx, __shfl_xor(mx, 4));
    float ex = __expf(sc - mx);
    float sm = ex;
    sm += __shfl_xor(sm, 1);
    sm += __shfl_xor(sm, 2);
    sm += __shfl_xor(sm, 4);
    float al = ex / sm;                 // valid on lanes 0..7

    // ---- member-row gathers (8 rows; 2 ushort4 per lane), alpha-weighted ----
    float4 sf4;
    {
        const float a0 = __shfl(al, grp);
        const int   u0 = __shfl(nd, grp);
        const float a1 = __shfl(al, 4 + grp);
        const int   u1 = __shfl(nd, 4 + grp);
        const float4 v0 = bf4_to_f4(*(const ushort4*)(fb + ((unsigned)u0 << 7) + sub * 8));
        const float4 v1 = bf4_to_f4(*(const ushort4*)(fb + ((unsigned)u1 << 7) + sub * 8));
        sf4.x = a0 * v0.x + a1 * v1.x;
        sf4.y = a0 * v0.y + a1 * v1.y;
        sf4.z = a0 * v0.z + a1 * v1.z;
        sf4.w = a0 * v0.w + a1 * v1.w;
    }

    // ---- merged neighbor gathers: 16 rows (4 independent loads) per iter,
    //      weight derived from entry index (no wcomp) ----
    float4 nb4 = {0.f, 0.f, 0.f, 0.f};
    for (int base = 0; base < n; base += 16) {
        #pragma unroll
        for (int j = 0; j < 4; ++j) {
            const int cbase = base + j * 4;       // uniform, 4-aligned
            int off;
            if (cbase < 64) off = __shfl(pkA, cbase + grp);
            else            off = __shfl(pkB, cbase - 64 + grp);
            const int idx = cbase + grp;
            const float w = (idx < hc) ? hw : ((idx < n) ? sw : 0.f);
            const float4 v = bf4_to_f4(*(const ushort4*)(fb + (unsigned)off + sub * 8));
            nb4.x += w * v.x; nb4.y += w * v.y;
            nb4.z += w * v.z; nb4.w += w * v.w;
        }
    }

    // ---- cross-group reduction (sum row-slot partials; all lanes end equal) ----
#define XRED(v4)                                            \
    v4.x += __shfl_xor(v4.x, 16); v4.x += __shfl_xor(v4.x, 32); \
    v4.y += __shfl_xor(v4.y, 16); v4.y += __shfl_xor(v4.y, 32); \
    v4.z += __shfl_xor(v4.z, 16); v4.z += __shfl_xor(v4.z, 32); \
    v4.w += __shfl_xor(v4.w, 16); v4.w += __shfl_xor(v4.w, 32);
    XRED(sf4)
    XRED(nb4)
#undef XRED

    // ---- rating-count correction (scaled by 0.5/hc); re loads late ----
    {
        const float4* re4p = (const float4*)r_embed;
        const float4 re0 = re4p[0 * 16 + sub];
        const float4 re1 = re4p[1 * 16 + sub];
        const float4 re2 = re4p[2 * 16 + sub];
        const float4 re3 = re4p[3 * 16 + sub];
        const float4 re4 = re4p[4 * 16 + sub];
        float f0 = hw * (float)c0, f1 = hw * (float)c1, f2 = hw * (float)c2,
              f3 = hw * (float)c3, f4 = hw * (float)c4;
        nb4.x += f0 * re0.x + f1 * re1.x + f2 * re2.x + f3 * re3.x + f4 * re4.x;
        nb4.y += f0 * re0.y + f1 * re1.y + f2 * re2.y + f3 * re3.y + f4 * re4.y;
        nb4.z += f0 * re0.z + f1 * re1.z + f2 * re2.z + f3 * re3.z + f4 * re4.z;
        nb4.w += f0 * re0.w + f1 * re1.w + f2 * re2.w + f3 * re3.w + f4 * re4.w;
    }

    // ---- park comb row (lcomp dead; wave-local, no barrier) ----
    if (grp == 0) *(float4*)&cb[sub * 4] = sf4;
    if (grp == 1) *(float4*)&cb[64 + sub * 4] = nb4;

    // ---- fused matvec, float4 w1 loads (32 VMEM/wave):
    //      lane (grp,sub) accumulates cols 4sub..4sub+3 over k = 4j+grp ----
    float4 p = {0.f, 0.f, 0.f, 0.f};
    #pragma unroll 8
    for (int j = 0; j < 32; ++j) {
        const float  c   = cb[j * 4 + grp];                    // LDS broadcast
        const float4 wv4 = *(const float4*)(w1 + (j * 4 + grp) * 64 + sub * 4);
        p.x += c * wv4.x;
        p.y += c * wv4.y;
        p.z += c * wv4.z;
        p.w += c * wv4.w;
    }
    // reduce the 4 k-residue partials across grp lanes
    p.x += __shfl_xor(p.x, 16); p.x += __shfl_xor(p.x, 32);
    p.y += __shfl_xor(p.y, 16); p.y += __shfl_xor(p.y, 32);
    p.z += __shfl_xor(p.z, 16); p.z += __shfl_xor(p.z, 32);
    p.w += __shfl_xor(p.w, 16); p.w += __shfl_xor(p.w, 32);
    if (grp == 0) {
        const float4 bv = *(const float4*)(b1 + sub * 4);
        float4 o;
        o.x = fmaxf(p.x + bv.x, 0.f);
        o.y = fmaxf(p.y + bv.y, 0.f);
        o.z = fmaxf(p.z + bv.z, 0.f);
        o.w = fmaxf(p.w + bv.w, 0.f);
        *(float4*)(out + (size_t)e * 64 + sub * 4) = o;
    }
}

extern "C" void kernel_launch(void* const* d_in, const int* in_sizes, int n_in,
                              void* d_out, int out_size, void* d_ws, size_t ws_size,
                              hipStream_t stream)
{
    const int*   nodes    = (const int*)d_in[0];
    const int*   hu       = (const int*)d_in[1];
    const int*   hr       = (const int*)d_in[2];
    const int*   hm       = (const int*)d_in[3];
    const int*   sa       = (const int*)d_in[4];
    const int*   smk      = (const int*)d_in[5];
    const float* features = (const float*)d_in[6];
    const float* r_embed  = (const float*)d_in[7];
    const float* wg1      = (const float*)d_in[8];
    const float* bg1      = (const float*)d_in[9];
    const float* wg2      = (const float*)d_in[10];
    const float* bg2      = (const float*)d_in[11];
    const float* w1       = (const float*)d_in[12];
    const float* b1       = (const float*)d_in[13];
    float* out = (float*)d_out;

    float*          Q   = (float*)d_ws;                    // 131072 floats (512 KB)
    unsigned short* fbf = (unsigned short*)(Q + 131072);   // 100000*64 bf16 = 12.8 MB

    k0_scores<<<NUSERS / 16, 256, 0, stream>>>(features, wg1, bg1, wg2, bg2, Q, fbf);
    k1_fuse<<<BB / 4, 256, 0, stream>>>(nodes, hu, hr, hm, sa, smk,
                                        fbf, r_embed, Q, w1, b1, out);
}